// Round 14
// baseline (202.893 us; speedup 1.0000x reference)
//
#include <hip/hip_runtime.h>

#define BH 64
#define S_ 4096
#define D_ 128
#define SCALE 0.25f  // 1/sqrt(n_heads=16)

typedef __attribute__((ext_vector_type(4))) short short4v;
typedef __attribute__((ext_vector_type(8))) short short8v;
typedef __attribute__((ext_vector_type(4))) float f32x4;

__device__ inline unsigned short f2bf(float x) {
  union { float f; unsigned u; } v; v.f = x;
  unsigned r = v.u + 0x7fff + ((v.u >> 16) & 1);
  return (unsigned short)(r >> 16);
}
__device__ inline short8v cat8(short4v a, short4v b) {
  short8v r;
  r[0] = a[0]; r[1] = a[1]; r[2] = a[2]; r[3] = a[3];
  r[4] = b[0]; r[5] = b[1]; r[6] = b[2]; r[7] = b[3];
  return r;
}
// Hardware transpose read (semantics verified rounds 2-13).
__device__ inline short4v tr16(unsigned addr) {
  short4v r;
  asm volatile("ds_read_b64_tr_b16 %0, %1" : "=v"(r) : "v"(addr));
  return r;
}
// Truncation-based hi/lo bf16 split of two floats, packed (elem0 in low 16).
__device__ inline void cvt_pair(float x0, float x1, unsigned& hi, unsigned& lo) {
  unsigned u0 = __float_as_uint(x0), u1 = __float_as_uint(x1);
  unsigned m0 = u0 & 0xffff0000u, m1 = u1 & 0xffff0000u;
  hi = m1 | (u0 >> 16);
  float l0 = x0 - __uint_as_float(m0);
  float l1 = x1 - __uint_as_float(m1);
  lo = (__float_as_uint(l1) & 0xffff0000u) | (__float_as_uint(l0) >> 16);
}

// ---------------------------------------------------------------------------
// Phase A: split-K QK^T — PRODUCER/CONSUMER wave specialization.
// Grid (bh=64, ks=16, dh=2): 2048 blocks x 256 threads.  Waves 0-1 consume
// (tr16 + MFMA only, never any vmem); waves 2-3 produce (float4 load + hi/lo
// cvt + ds_write only, never tr16/MFMA).  3-slot LDS ring (3 x 24 KB = 72 KB,
// 2 blocks/CU), one s_barrier per step.
//
// Slot layout (24 KB): Qhi[32s x 64d] @0 | Qlo @4K | Khi[32s x 128e] @8K |
// Klo @16K — each tile in the R6/R10-verified 4x16-subtile layout:
//   C=64 : slot s -> row ((s>>6)<<2)|((s>>2)&3), col (((s>>4)&3)<<4)|((s&3)<<2)
//   C=128: slot s -> row ((s>>7)<<2)|((s>>2)&3), col (((s>>4)&7)<<4)|((s&3)<<2)
//
// Ring audit: step st consumers read slot st%3, producers write slot
// (st+2)%3 (mod-3 => never equal).  Slot (st+2)%3 was last read at step
// st-1; those tr16s are lgkm-drained before barrier(st-1), and producer
// writes begin after barrier(st-1).  Producer writes are lgkm-drained
// before barrier(st); consumed at step st+2 (two barriers later).  Producer
// loads cross barriers un-drained (consumed only by own cvt next step).
// ---------------------------------------------------------------------------
template <int NKS, bool ATOMIC>
__global__ __launch_bounds__(256) void qk_ws(const float* __restrict__ q,
                                             const float* __restrict__ k,
                                             float* __restrict__ part) {
  constexpr int nsteps = S_ / NKS / 32;  // 8 at NKS=16
  static_assert(nsteps % 2 == 0, "even steps for regset pairing");
  const int bh = blockIdx.x;
  const int ks = blockIdx.y;
  const int dh = blockIdx.z;
  const float* qb = q + ((size_t)bh * S_ + ks * (S_ / NKS)) * D_ + dh * 64;
  const float* kb = k + ((size_t)bh * S_ + ks * (S_ / NKS)) * D_;

  __shared__ alignas(16) short lds[3 * 12288];  // 3 slots x 24 KB
  const unsigned base_b = (unsigned)(uintptr_t)&lds[0];

  const int tid = threadIdx.x;
  const int wv = tid >> 6, lane = tid & 63;
  const bool producer = wv >= 2;

  // ---------------- producer state ----------------
  const int p = tid & 127;  // producer index 0..127 (waves 2,3)
  float4 qA[4], kA[8], qB[4], kB[8];

  auto loadQK = [&](int st, float4 (&qr)[4], float4 (&kr)[8]) {
#pragma unroll
    for (int j = 0; j < 4; ++j) {
      int s = p + j * 128;
      int row = ((s >> 6) << 2) | ((s >> 2) & 3);
      int col = (((s >> 4) & 3) << 4) | ((s & 3) << 2);
      qr[j] = *(const float4*)(qb + (size_t)(st * 32 + row) * D_ + col);
    }
#pragma unroll
    for (int j = 0; j < 8; ++j) {
      int s = p + j * 128;
      int row = ((s >> 7) << 2) | ((s >> 2) & 3);
      int col = (((s >> 4) & 7) << 4) | ((s & 3) << 2);
      kr[j] = *(const float4*)(kb + (size_t)(st * 32 + row) * D_ + col);
    }
  };
  auto writeQK = [&](int slot, float4 (&qr)[4], float4 (&kr)[8]) {
    unsigned* U = (unsigned*)&lds[slot * 12288];
#pragma unroll
    for (int j = 0; j < 4; ++j) {
      unsigned off = (unsigned)(p + j * 128) * 2;
      unsigned h0, l0, h1, l1;
      cvt_pair(qr[j].x, qr[j].y, h0, l0);
      cvt_pair(qr[j].z, qr[j].w, h1, l1);
      *(uint2*)(U + off) = make_uint2(h0, h1);          // Qhi
      *(uint2*)(U + 1024 + off) = make_uint2(l0, l1);   // Qlo
    }
#pragma unroll
    for (int j = 0; j < 8; ++j) {
      unsigned off = (unsigned)(p + j * 128) * 2;
      unsigned h0, l0, h1, l1;
      cvt_pair(kr[j].x, kr[j].y, h0, l0);
      cvt_pair(kr[j].z, kr[j].w, h1, l1);
      *(uint2*)(U + 2048 + off) = make_uint2(h0, h1);   // Khi
      *(uint2*)(U + 4096 + off) = make_uint2(l0, l1);   // Klo
    }
  };

  // ---------------- consumer state ----------------
  f32x4 acc[2][8];
#pragma unroll
  for (int a = 0; a < 2; ++a)
#pragma unroll
    for (int n = 0; n < 8; ++n) acc[a][n] = (f32x4){0.f, 0.f, 0.f, 0.f};

  const unsigned lq = ((unsigned)(lane >> 4) << 9) |
                      ((unsigned)((lane & 15) >> 2) << 5) |
                      ((unsigned)(lane & 3) << 3);
  const unsigned lk = ((unsigned)(lane >> 4) << 10) |
                      ((unsigned)((lane & 15) >> 2) << 5) |
                      ((unsigned)(lane & 3) << 3);

  auto cstep = [&](int slot) {
    const unsigned sb = base_b + (unsigned)slot * 24576;
    short4v Bf[8][2][2];
#pragma unroll
    for (int n = 0; n < 8; ++n)
#pragma unroll
      for (int ver = 0; ver < 2; ++ver)
#pragma unroll
        for (int kh = 0; kh < 2; ++kh)
          Bf[n][ver][kh] =
              tr16(sb + 8192 + lk + ver * 8192 + kh * 4096 + (n << 7));
    short4v Af[2][2][2];
#pragma unroll
    for (int a = 0; a < 2; ++a)
#pragma unroll
      for (int ver = 0; ver < 2; ++ver)
#pragma unroll
        for (int kh = 0; kh < 2; ++kh)
          Af[a][ver][kh] =
              tr16(sb + lq + ver * 4096 + kh * 2048 + ((wv * 2 + a) << 7));
    asm volatile("s_waitcnt lgkmcnt(0)" ::: "memory");  // rule-18 fence
    __builtin_amdgcn_sched_barrier(0);
#pragma unroll
    for (int a = 0; a < 2; ++a) {
      short8v ah = cat8(Af[a][0][0], Af[a][0][1]);
      short8v al = cat8(Af[a][1][0], Af[a][1][1]);
#pragma unroll
      for (int n = 0; n < 8; ++n) {
        short8v bh_ = cat8(Bf[n][0][0], Bf[n][0][1]);
        short8v bl_ = cat8(Bf[n][1][0], Bf[n][1][1]);
        acc[a][n] = __builtin_amdgcn_mfma_f32_16x16x32_bf16(ah, bh_, acc[a][n], 0, 0, 0);
        acc[a][n] = __builtin_amdgcn_mfma_f32_16x16x32_bf16(ah, bl_, acc[a][n], 0, 0, 0);
        acc[a][n] = __builtin_amdgcn_mfma_f32_16x16x32_bf16(al, bh_, acc[a][n], 0, 0, 0);
      }
    }
  };

  // ---------------- prologue ----------------
  if (producer) {
    loadQK(0, qA, kA);
    loadQK(1, qB, kB);
    writeQK(0, qA, kA);     // cvt use-waits chunk-0 loads
    loadQK(2, qA, kA);      // regset A free after cvt consumed it
    writeQK(1, qB, kB);
    asm volatile("s_waitcnt lgkmcnt(0)" ::: "memory");
  }
  __builtin_amdgcn_s_barrier();

  // ---------------- main loop (unrolled x2 for static regsets) ----------
  for (int st = 0; st < nsteps; st += 2) {
    if (producer) {
      if (st + 2 < nsteps) writeQK((st + 2) % 3, qA, kA);  // chunk st+2
      if (st + 3 < nsteps) loadQK(st + 3, qB, kB);
      asm volatile("s_waitcnt lgkmcnt(0)" ::: "memory");
    } else {
      cstep(st % 3);
    }
    __builtin_amdgcn_s_barrier();
    if (producer) {
      if (st + 3 < nsteps) writeQK((st + 3) % 3, qB, kB);  // chunk st+3
      if (st + 4 < nsteps) loadQK(st + 4, qA, kA);
      asm volatile("s_waitcnt lgkmcnt(0)" ::: "memory");
    } else {
      cstep((st + 1) % 3);
    }
    __builtin_amdgcn_s_barrier();
  }

  // ---------------- epilogue (consumers only) ----------------
  if (!producer) {
    if (!ATOMIC) {
      float* dst = part + ((size_t)ks * BH + bh) * D_ * D_;
#pragma unroll
      for (int a = 0; a < 2; ++a)
#pragma unroll
        for (int n = 0; n < 8; ++n) {
          int e = n * 16 + (lane & 15);
#pragma unroll
          for (int r = 0; r < 4; ++r) {
            int d = dh * 64 + (wv * 2 + a) * 16 + ((lane >> 4) << 2) + r;
            dst[(size_t)d * D_ + e] = acc[a][n][r] * SCALE;
          }
        }
    } else {
      float* dst = part + (size_t)bh * D_ * D_;
#pragma unroll
      for (int a = 0; a < 2; ++a)
#pragma unroll
        for (int n = 0; n < 8; ++n) {
          int e = n * 16 + (lane & 15);
#pragma unroll
          for (int r = 0; r < 4; ++r) {
            int d = dh * 64 + (wv * 2 + a) * 16 + ((lane >> 4) << 2) + r;
            atomicAdd(&dst[(size_t)d * D_ + e], acc[a][n][r] * SCALE);
          }
        }
    }
  }
}

// ---------------------------------------------------------------------------
// Phase B: combine partials + row softmax -> P as bf16 (linear [d][e])
// ---------------------------------------------------------------------------
template <int NKS>
__global__ __launch_bounds__(256) void softmax_k(const float* __restrict__ part,
                                                 short* __restrict__ Pg) {
  const int bh = blockIdx.x;
  const int wv = threadIdx.x >> 6, lane = threadIdx.x & 63;
  const size_t kstride = (size_t)BH * D_ * D_;
  const float* base = part + (size_t)bh * D_ * D_;
  short* dst = Pg + (size_t)bh * D_ * D_;
#pragma unroll
  for (int i = 0; i < 8; ++i) {
    int d = blockIdx.y * 32 + wv * 8 + i;
    float v0 = 0.f, v1 = 0.f;
    for (int ks2 = 0; ks2 < NKS; ++ks2) {
      const float* row = base + ks2 * kstride + (size_t)d * D_;
      v0 += row[lane];
      v1 += row[lane + 64];
    }
    float m = fmaxf(v0, v1);
#pragma unroll
    for (int off = 32; off; off >>= 1) m = fmaxf(m, __shfl_xor(m, off, 64));
    float e0 = __expf(v0 - m), e1 = __expf(v1 - m);
    float s = e0 + e1;
#pragma unroll
    for (int off = 32; off; off >>= 1) s += __shfl_xor(s, off, 64);
    float inv = 1.f / s;
    dst[(size_t)d * D_ + lane] = (short)f2bf(e0 * inv);
    dst[(size_t)d * D_ + lane + 64] = (short)f2bf(e1 * inv);
  }
}

// ---------------------------------------------------------------------------
// Phase C: out[d][s] = sum_e P[d][e] * v[s][e] — bf16 MFMA over contiguous e.
// ---------------------------------------------------------------------------
__global__ __launch_bounds__(256) void pv_mfma(const short* __restrict__ Pg,
                                               const float* __restrict__ v,
                                               float* __restrict__ out) {
  const int bh = blockIdx.x;
  const int s0 = blockIdx.y * 128;
  const float* vb = v + (size_t)bh * S_ * D_;
  __shared__ alignas(16) short P_lds[128 * 136];
  __shared__ alignas(16) short V_lds[128 * 36];
  const int tid = threadIdx.x;
  const int wv = tid >> 6, lane = tid & 63;

  const short* Pb = Pg + (size_t)bh * D_ * D_;
#pragma unroll
  for (int i = 0; i < 8; ++i) {
    int idx8 = tid + i * 256;
    int row = idx8 >> 4, c8 = idx8 & 15;
    short8v val = *(const short8v*)(Pb + row * 128 + c8 * 8);
    *(short8v*)(P_lds + row * 136 + c8 * 8) = val;
  }

  f32x4 acc[8][2];
#pragma unroll
  for (int i = 0; i < 8; ++i)
#pragma unroll
    for (int j = 0; j < 2; ++j) acc[i][j] = (f32x4){0.f, 0.f, 0.f, 0.f};

#pragma unroll
  for (int es = 0; es < 4; ++es) {
    __syncthreads();
#pragma unroll
    for (int i = 0; i < 4; ++i) {
      int idx4 = tid + i * 256;
      int s = idx4 >> 3, c4 = idx4 & 7;
      float4 x = *(const float4*)(vb + (size_t)(s0 + s) * D_ + es * 32 + c4 * 4);
      short4v h;
      h[0] = (short)f2bf(x.x); h[1] = (short)f2bf(x.y);
      h[2] = (short)f2bf(x.z); h[3] = (short)f2bf(x.w);
      *(short4v*)(V_lds + s * 36 + c4 * 4) = h;
    }
    __syncthreads();

    short8v a[8];
#pragma unroll
    for (int mt = 0; mt < 8; ++mt) {
      int d = mt * 16 + (lane & 15);
      const short* pr = P_lds + d * 136 + es * 32 + ((lane >> 4) << 2);
      a[mt] = cat8(*(const short4v*)pr, *(const short4v*)(pr + 16));
    }
#pragma unroll
    for (int nl = 0; nl < 2; ++nl) {
      int srow = (wv * 2 + nl) * 16 + (lane & 15);
      const short* vr = V_lds + srow * 36 + ((lane >> 4) << 2);
      short8v b = cat8(*(const short4v*)vr, *(const short4v*)(vr + 16));
#pragma unroll
      for (int mt = 0; mt < 8; ++mt)
        acc[mt][nl] = __builtin_amdgcn_mfma_f32_16x16x32_bf16(a[mt], b, acc[mt][nl], 0, 0, 0);
    }
  }

  float* ob = out + (size_t)bh * D_ * S_ + s0;
#pragma unroll
  for (int mt = 0; mt < 8; ++mt)
#pragma unroll
    for (int nl = 0; nl < 2; ++nl) {
      int sc = (wv * 2 + nl) * 16 + (lane & 15);
#pragma unroll
      for (int r = 0; r < 4; ++r) {
        int d = mt * 16 + ((lane >> 4) << 2) + r;
        ob[(size_t)d * S_ + sc] = acc[mt][nl][r];
      }
    }
}

extern "C" void kernel_launch(void* const* d_in, const int* in_sizes, int n_in,
                              void* d_out, int out_size, void* d_ws,
                              size_t ws_size, hipStream_t stream) {
  const float* q = (const float*)d_in[0];
  const float* k = (const float*)d_in[1];
  const float* v = (const float*)d_in[2];
  float* out = (float*)d_out;
  char* ws = (char*)d_ws;

  const size_t PART1 = (size_t)BH * D_ * D_ * sizeof(float);  // 4 MiB
  const size_t PSZ = (size_t)BH * D_ * D_ * sizeof(short);    // 2 MiB

  if (ws_size >= 16 * PART1 + PSZ) {
    float* part = (float*)ws;
    short* Pg = (short*)(ws + 16 * PART1);
    qk_ws<16, false><<<dim3(BH, 16, 2), 256, 0, stream>>>(q, k, part);
    softmax_k<16><<<dim3(BH, 4), 256, 0, stream>>>(part, Pg);
    pv_mfma<<<dim3(BH, 32), 256, 0, stream>>>(Pg, v, out);
  } else {
    float* part = (float*)ws;
    short* Pg = (short*)(ws + PART1);
    hipMemsetAsync(ws, 0, PART1, stream);
    qk_ws<16, true><<<dim3(BH, 16, 2), 256, 0, stream>>>(q, k, part);
    softmax_k<1><<<dim3(BH, 4), 256, 0, stream>>>(part, Pg);
    pv_mfma<<<dim3(BH, 32), 256, 0, stream>>>(Pg, v, out);
  }
}